// Round 13
// baseline (125.735 us; speedup 1.0000x reference)
//
#include <hip/hip_runtime.h>

// SLAYER 2-layer SNN, MI355X. Round-13: single fused tile kernel.
// r12 falsified conv-issue-boundedness; ~20-25us of the 55us kernel budget is
// launch/boundary overhead. Fix: merge L1+L2 into one 576-block kernel that
// computes the 18x18 s1 halo in-block (1.27x conv1 amplification, identical
// arithmetic -> identical bits), 45KB LDS -> 3 blocks/CU, grid 2.25/CU =
// fully co-resident. KA (bit-pack) stays separate (needs global view).
//   KA: floats -> bitT[y][xw][t]                         [1152 blocks]
//   LF: 3 groups x (VALU conv1 6 s1-rows -> ct -> scan1 108 px) -> s1b LDS
//       -> t-transpose wrow -> conv2 patterns -> scan2 (lut3) -> out
// All sum associations and scan ops identical to rounds 0-12 (absmax == 0).

#define HH   192
#define WW   192
#define NIMG 4
#define TT   64
#define NT   256
#define XW   6     // uint32 x-words per image row

#define E_D 2.718281828459045
static constexpr float D1  = (float)0.36787944117144233;   // exp(-1/1)
static constexpr float CP1 = (float)(E_D);
static constexpr float DR1 = (float)0.36787944117144233;
static constexpr float CR1 = (float)(-30.0 * E_D);
static constexpr float D2  = (float)0.6065306597126334;    // exp(-1/2)
static constexpr float CP2 = (float)(E_D * 0.5);
static constexpr float DR2 = (float)0.6065306597126334;
static constexpr float CR2 = (float)(-50.0 * E_D * 0.5);
static constexpr float TH1 = 30.0f;
static constexpr float TH2 = 50.0f;

// ---------------- KA: float spikes -> x-transposed bit words ---------------
__global__ __launch_bounds__(NT)
void ka_pack(const float* __restrict__ in, unsigned* __restrict__ bitT) {
    const int gw = blockIdx.x * (NT / 64) + (threadIdx.x >> 6);
    const int ln = threadIdx.x & 63;
    const int xw = gw % XW;
    const int ny = gw / XW;                 // n*HH + y
    const float* src = in + ((size_t)ny * WW + xw * 32) * TT + ln;
    unsigned w = 0u;
#pragma unroll
    for (int x = 0; x < 32; x++) {
        const float v = src[(size_t)x * TT];
        w |= (v != 0.f) ? (1u << x) : 0u;
    }
    bitT[((size_t)ny * XW + xw) * TT + ln] = w;
}

// ---------------- LF: fused conv1+scan1 (18x18 halo) + conv2+scan2 ---------
// Block: 16x16 output tile, 256 threads. Grid 12 x 12 x 4 = 576 blocks.
__global__ __launch_bounds__(NT, 4)
void lf_fused(const unsigned* __restrict__ bitT, const float* __restrict__ w1g,
              const float* __restrict__ w2g, float* __restrict__ out) {
    __shared__ float    ubuf[8448];        // ct[108*65] f32 | ptile[256*66] u16
    __shared__ uint2    s1b[18 * 18];      // s1 bits, px-major (halo domain)
    __shared__ unsigned wrow[18 * 64];     // s1 rows t-major, bit c = s1 col c
    __shared__ uint2    tb[NT];
    __shared__ float    lut3[512];

    float*          ct    = ubuf;
    unsigned short* ptile = (unsigned short*)ubuf;

    const int n = blockIdx.z, ty = blockIdx.y, tx = blockIdx.x;
    const int y0 = ty * 16, x0 = tx * 16;
    const int tid = threadIdx.x;
    const int wv = tid >> 6, ln = tid & 63;

    // Weights + lut3 (lut3[e] = (l0+l1)+l2, j-order == rounds 5-12 bitwise).
    float w1r[25];
#pragma unroll
    for (int k = 0; k < 25; k++) w1r[k] = w1g[k];
#pragma unroll
    for (int e = tid; e < 512; e += NT) {
        float l0 = 0.f, l1 = 0.f, l2 = 0.f;
#pragma unroll
        for (int j = 0; j < 3; j++) {
            if ((e >> j) & 1)       l0 += w2g[j];
            if ((e >> (3 + j)) & 1) l1 += w2g[3 + j];
            if ((e >> (6 + j)) & 1) l2 += w2g[6 + j];
        }
        lut3[e] = (l0 + l1) + l2;
    }

    // Window geometry: w22 bit c <-> gx = x0-3+c (c=0..21); s1 col cc uses
    // bits cc..cc+4 (s1 gx = x0-1+cc). Shift s in {29,13}, never 0.
    const int a = (x0 - 3) >> 5;
    const int s = (x0 - 3) & 31;

    // ---- 3 groups of 6 s1-rows: conv1 (lanes=t) then scan1 (lane=px) ------
#pragma unroll
    for (int g = 0; g < 3; g++) {
        // conv1: wave wv does sub=wv (all) and sub=4+wv (waves 0-1).
#pragma unroll
        for (int pass = 0; pass < 2; pass++) {
            const int sub = pass * 4 + wv;
            if (sub < 6) {
                const int r = g * 6 + sub;           // s1 halo row 0..17
                const int gy1 = y0 - 1 + r;          // s1 image row
                unsigned w22[5];
#pragma unroll
                for (int dy = 0; dy < 5; dy++) {
                    const int gy = gy1 - 2 + dy;
                    unsigned wa = 0u, wb = 0u;
                    if (gy >= 0 && gy < HH) {
                        const unsigned* rp =
                            bitT + ((size_t)(n * HH + gy) * XW) * TT + ln;
                        if (a >= 0)     wa = rp[(size_t)a * TT];
                        if (a + 1 < XW) wb = rp[(size_t)(a + 1) * TT];
                    }
                    w22[dy] = (wa >> s) | (wb << (32 - s));
                }
#pragma unroll
                for (int cc = 0; cc < 18; cc++) {
                    float l0 = 0.f, l1 = 0.f, l2 = 0.f, l3 = 0.f, l4 = 0.f;
#pragma unroll
                    for (int j = 0; j < 5; j++) {
                        l0 += (float)((w22[0] >> (cc + j)) & 1u) * w1r[j];
                        l1 += (float)((w22[1] >> (cc + j)) & 1u) * w1r[5 + j];
                        l2 += (float)((w22[2] >> (cc + j)) & 1u) * w1r[10 + j];
                        l3 += (float)((w22[3] >> (cc + j)) & 1u) * w1r[15 + j];
                        l4 += (float)((w22[4] >> (cc + j)) & 1u) * w1r[20 + j];
                    }
                    ct[(sub * 18 + cc) * 65 + ln] = ((l0 + l1) + (l2 + l3)) + l4;
                }
            }
        }
        __syncthreads();

        // scan1: 108 px on waves 0-1. Op-identical to rounds 0-12.
        if (tid < 108) {
            const int px = tid;
            const int sub = px / 18, cc = px - sub * 18;
            const int r = g * 6 + sub;
            float u1 = 0.f, v1 = 0.f, ur = 0.f, vr = 0.f;
            unsigned slo = 0u, shi = 0u;
#pragma unroll
            for (int tc = 0; tc < TT; tc += 8) {
                float c8[8];
#pragma unroll
                for (int j = 0; j < 8; j++) c8[j] = ct[px * 65 + tc + j];
#pragma unroll
                for (int j = 0; j < 8; j++) {
                    v1 = D1 * (v1 + u1);
                    const float p = CP1 * v1;
                    u1 = D1 * u1 + c8[j];
                    vr = DR1 * (vr + ur);
                    const float m = p + CR1 * vr;
                    const bool sp = (m >= TH1);
                    ur = DR1 * ur + (sp ? 1.f : 0.f);
                    const unsigned bit = sp ? (1u << ((tc + j) & 31)) : 0u;
                    if (tc < 32) slo |= bit;
                    else         shi |= bit;
                }
            }
            // zero-pad: s1 outside the image contributes 0 to conv2
            const int gy1 = y0 - 1 + r, gx1 = x0 - 1 + cc;
            const bool valid = (gy1 >= 0 && gy1 < HH && gx1 >= 0 && gx1 < WW);
            s1b[r * 18 + cc] = make_uint2(valid ? slo : 0u, valid ? shi : 0u);
        }
        __syncthreads();                   // s1b ready; ct reusable next group
    }

    // ---- transpose s1b -> wrow (t-major 18-bit words) ----------------------
    for (int r = wv; r < 18; r += 4) {
        unsigned h = 0u;
#pragma unroll
        for (int c = 0; c < 18; c++) {
            const uint2 b = s1b[r * 18 + c];         // LDS broadcast
            const unsigned w = (ln < 32) ? b.x : b.y;
            h |= ((w >> (ln & 31)) & 1u) << c;
        }
        wrow[r * 64 + ln] = h;
    }
    __syncthreads();

    // ---- conv2 patterns: wave wv -> out rows wv*4..wv*4+3 (lanes=t) -------
#pragma unroll
    for (int rp = 0; rp < 4; rp++) {
        const int orow = wv * 4 + rp;
        const unsigned h0 = wrow[(orow + 0) * 64 + ln];
        const unsigned h1 = wrow[(orow + 1) * 64 + ln];
        const unsigned h2 = wrow[(orow + 2) * 64 + ln];
#pragma unroll
        for (int oc = 0; oc < 16; oc++) {
            const unsigned pat = ((h0 >> oc) & 7)
                               | (((h1 >> oc) & 7) << 3)
                               | (((h2 >> oc) & 7) << 6);
            ptile[(orow * 16 + oc) * 66 + ln] = (unsigned short)pat;
        }
    }
    __syncthreads();

    // ---- scan2: 256 px, 1 px/thread, batched lut3 gathers (r8-r12) --------
    {
        const int px = tid;
        const unsigned* pp = (const unsigned*)(ptile + px * 66);  // 2 pats/word
        float u2 = 0.f, v2 = 0.f, ur2 = 0.f, vr2 = 0.f;
        unsigned olo = 0u, ohi = 0u;
#pragma unroll
        for (int tc = 0; tc < TT; tc += 8) {
            unsigned q[4];
#pragma unroll
            for (int k = 0; k < 4; k++) q[k] = pp[tc / 2 + k];
            float l[8];
#pragma unroll
            for (int k = 0; k < 4; k++) {
                l[2 * k + 0] = lut3[q[k] & 0x1ffu];
                l[2 * k + 1] = lut3[(q[k] >> 16) & 0x1ffu];
            }
#pragma unroll
            for (int j = 0; j < 8; j++) {
                v2 = D2 * (v2 + u2);
                const float p = CP2 * v2;
                u2 = D2 * u2 + l[j];
                vr2 = DR2 * (vr2 + ur2);
                const float m = p + CR2 * vr2;
                const bool sp = (m >= TH2);
                ur2 = DR2 * ur2 + (sp ? 1.f : 0.f);
                const unsigned bit = sp ? (1u << ((tc + j) & 31)) : 0u;
                if (tc < 32) olo |= bit;
                else         ohi |= bit;
            }
        }
        tb[px] = make_uint2(olo, ohi);
    }
    __syncthreads();

    // ---- epilogue: lanes=t, 256B contiguous stores (r5/r7 verified) -------
    const int sh = ln & 31;
#pragma unroll
    for (int k = 0; k < 64; k++) {
        const int p = wv * 64 + k;
        const uint2 b = tb[p];                       // LDS broadcast
        const unsigned w = (ln < 32) ? b.x : b.y;
        out[((size_t)(n * HH + y0 + (p >> 4)) * WW + x0 + (p & 15)) * TT + ln] =
            (float)((w >> sh) & 1u);
    }
}

extern "C" void kernel_launch(void* const* d_in, const int* in_sizes, int n_in,
                              void* d_out, int out_size, void* d_ws, size_t ws_size,
                              hipStream_t stream) {
    const float* in = (const float*)d_in[0];   // (4,1,192,192,64) f32 spikes
    const float* w1 = (const float*)d_in[1];   // (1,1,5,5)
    const float* w2 = (const float*)d_in[2];   // (1,1,3,3)
    float* out = (float*)d_out;                // (4,1,192,192,64) f32 spikes

    unsigned* bitT = (unsigned*)d_ws;          // 1.18 MB scratch

    const int ka_blocks = (NIMG * HH * XW) / (NT / 64);   // 1152
    dim3 fgrid(WW / 16, HH / 16, NIMG);                   // 12 x 12 x 4 = 576
    ka_pack <<<ka_blocks, NT, 0, stream>>>(in, bitT);
    lf_fused<<<fgrid, NT, 0, stream>>>(bitT, w1, w2, out);
}